// Round 1
// baseline (756.321 us; speedup 1.0000x reference)
//
#include <hip/hip_runtime.h>

constexpr int N  = 100000;
constexpr int E  = 1600000;
constexpr int IN = 128, HID = 64, OUTC = 32;

// ---------------- degree / norm ----------------
__global__ void k_deg(const int* __restrict__ dst, float* __restrict__ deg) {
    int t = blockIdx.x * blockDim.x + threadIdx.x;
    if (t < E) atomicAdd(&deg[dst[t]], 1.0f);
}

__global__ void k_dinv(float* __restrict__ deg) {
    int t = blockIdx.x * blockDim.x + threadIdx.x;
    if (t < N) deg[t] = rsqrtf(deg[t] + 1.0f);   // +1 = self loop; always > 0
}

// ---------------- GEMM1: H = X @ W1  (N x 128 @ 128 x 64) ----------------
__global__ __launch_bounds__(256) void k_gemm1(const float* __restrict__ X,
                                               const float* __restrict__ W,
                                               float* __restrict__ H) {
    constexpr int R  = 32;
    constexpr int XS = IN + 4;                 // pad to break bank conflicts
    __shared__ float ws[IN * HID];             // 32 KB
    __shared__ float xs[R * XS];               // ~16.5 KB
    const int t    = threadIdx.x;
    const int row0 = blockIdx.x * R;           // N/R = 3125 exact

    for (int i = t; i < IN * HID / 4; i += 256)
        ((float4*)ws)[i] = ((const float4*)W)[i];
    for (int i = t; i < R * IN / 4; i += 256) {
        int r = i / (IN / 4), k4 = i % (IN / 4);
        *(float4*)&xs[r * XS + k4 * 4] =
            ((const float4*)(X + (size_t)(row0 + r) * IN))[k4];
    }
    __syncthreads();

    const int col0 = (t & 15) * 4;             // 16 groups x 4 cols = 64 cols
    const int r0   = (t >> 4) * 2;             // 16 pairs -> 32 rows
    float4 a0 = {0, 0, 0, 0}, a1 = {0, 0, 0, 0};
    for (int k = 0; k < IN; ++k) {
        float4 w = *(const float4*)&ws[k * HID + col0];
        float x0 = xs[r0 * XS + k];
        float x1 = xs[(r0 + 1) * XS + k];
        a0.x += x0 * w.x; a0.y += x0 * w.y; a0.z += x0 * w.z; a0.w += x0 * w.w;
        a1.x += x1 * w.x; a1.y += x1 * w.y; a1.z += x1 * w.z; a1.w += x1 * w.w;
    }
    float* h0 = H + (size_t)(row0 + r0) * HID + col0;
    *(float4*)h0         = a0;
    *(float4*)(h0 + HID) = a1;
}

// ---------------- init OUT1 = H*dinv^2 + b1 ----------------
__global__ void k_init1(const float* __restrict__ H, const float* __restrict__ dinv,
                        const float* __restrict__ b, float* __restrict__ O) {
    int t = blockIdx.x * blockDim.x + threadIdx.x;
    if (t < N * HID) {
        int i = t >> 6, c = t & 63;
        float dn = dinv[i];
        O[t] = H[t] * dn * dn + b[c];
    }
}

// ---------------- scatter1: OUT1[dst] += H[src]*norm  (1 edge / wave) ----------------
__global__ __launch_bounds__(256) void k_scatter1(const int* __restrict__ src,
                                                  const int* __restrict__ dst,
                                                  const float* __restrict__ dinv,
                                                  const float* __restrict__ H,
                                                  float* __restrict__ O) {
    long long g = (long long)blockIdx.x * 256 + threadIdx.x;
    int e = (int)(g >> 6);
    int c = (int)(g & 63);
    if (e >= E) return;
    int s = src[e], d = dst[e];
    float nrm = dinv[s] * dinv[d];
    atomicAdd(&O[(size_t)d * HID + c], H[(size_t)s * HID + c] * nrm);
}

// ---------------- GEMM2: H2 = relu(OUT1) @ W2  (N x 64 @ 64 x 32) ----------------
__global__ __launch_bounds__(256) void k_gemm2(const float* __restrict__ O1,
                                               const float* __restrict__ W,
                                               float* __restrict__ H2) {
    constexpr int R  = 32;
    constexpr int XS = HID + 4;                // 68
    __shared__ float ws[HID * OUTC];           // 8 KB
    __shared__ float xs[R * XS];               // ~8.5 KB
    const int t    = threadIdx.x;
    const int row0 = blockIdx.x * R;           // 3125 blocks exact

    for (int i = t; i < HID * OUTC / 4; i += 256)
        ((float4*)ws)[i] = ((const float4*)W)[i];
    for (int i = t; i < R * HID / 4; i += 256) {
        int r = i / (HID / 4), k4 = i % (HID / 4);
        float4 v = ((const float4*)(O1 + (size_t)(row0 + r) * HID))[k4];
        v.x = fmaxf(v.x, 0.f); v.y = fmaxf(v.y, 0.f);
        v.z = fmaxf(v.z, 0.f); v.w = fmaxf(v.w, 0.f);
        *(float4*)&xs[r * XS + k4 * 4] = v;
    }
    __syncthreads();

    const int col0 = (t & 7) * 4;              // 8 groups x 4 cols = 32 cols
    const int r    = t >> 3;                   // 32 rows
    float4 a = {0, 0, 0, 0};
    for (int k = 0; k < HID; ++k) {
        float4 w = *(const float4*)&ws[k * OUTC + col0];
        float x  = xs[r * XS + k];
        a.x += x * w.x; a.y += x * w.y; a.z += x * w.z; a.w += x * w.w;
    }
    *(float4*)(H2 + (size_t)(row0 + r) * OUTC + col0) = a;
}

// ---------------- init OUT = H2*dinv^2 + b2 ----------------
__global__ void k_init2(const float* __restrict__ H2, const float* __restrict__ dinv,
                        const float* __restrict__ b, float* __restrict__ O) {
    int t = blockIdx.x * blockDim.x + threadIdx.x;
    if (t < N * OUTC) {
        int i = t >> 5, c = t & 31;
        float dn = dinv[i];
        O[t] = H2[t] * dn * dn + b[c];
    }
}

// ---------------- scatter2: OUT[dst] += H2[src]*norm  (2 edges / wave) ----------------
__global__ __launch_bounds__(256) void k_scatter2(const int* __restrict__ src,
                                                  const int* __restrict__ dst,
                                                  const float* __restrict__ dinv,
                                                  const float* __restrict__ H2,
                                                  float* __restrict__ O) {
    long long g = (long long)blockIdx.x * 256 + threadIdx.x;
    int e = (int)(g >> 5);
    int c = (int)(g & 31);
    if (e >= E) return;
    int s = src[e], d = dst[e];
    float nrm = dinv[s] * dinv[d];
    atomicAdd(&O[(size_t)d * OUTC + c], H2[(size_t)s * OUTC + c] * nrm);
}

extern "C" void kernel_launch(void* const* d_in, const int* in_sizes, int n_in,
                              void* d_out, int out_size, void* d_ws, size_t ws_size,
                              hipStream_t stream) {
    const float* x   = (const float*)d_in[0];
    const int*   ei  = (const int*)d_in[1];     // [2, E]: row0 = src, row1 = dst
    const float* W1  = (const float*)d_in[2];
    const float* b1  = (const float*)d_in[3];
    const float* W2  = (const float*)d_in[4];
    const float* b2  = (const float*)d_in[5];
    float*       out = (float*)d_out;

    const int* srcp = ei;
    const int* dstp = ei + E;

    char* ws = (char*)d_ws;
    // layout: dinv [0, 400000) | H/H2 [1 MB, +25.6 MB) | OUT1 [27 MB, +25.6 MB)
    float* dinv = (float*)(ws);
    float* H    = (float*)(ws + (1u << 20));
    float* O1   = (float*)(ws + 27u * (1u << 20));
    float* H2   = H;                             // reuse: H dead after scatter1

    hipMemsetAsync(dinv, 0, N * sizeof(float), stream);

    k_deg<<<(E + 255) / 256, 256, 0, stream>>>(dstp, dinv);
    k_dinv<<<(N + 255) / 256, 256, 0, stream>>>(dinv);

    k_gemm1<<<N / 32, 256, 0, stream>>>(x, W1, H);
    k_init1<<<(N * HID + 255) / 256, 256, 0, stream>>>(H, dinv, b1, O1);
    {
        long long threads = (long long)E * 64;
        k_scatter1<<<(unsigned)((threads + 255) / 256), 256, 0, stream>>>(srcp, dstp, dinv, H, O1);
    }
    k_gemm2<<<N / 32, 256, 0, stream>>>(O1, W2, H2);
    k_init2<<<(N * OUTC + 255) / 256, 256, 0, stream>>>(H2, dinv, b2, out);
    {
        long long threads = (long long)E * 32;
        k_scatter2<<<(unsigned)((threads + 255) / 256), 256, 0, stream>>>(srcp, dstp, dinv, H2, out);
    }
}

// Round 2
// 506.809 us; speedup vs baseline: 1.4923x; 1.4923x over previous
//
#include <hip/hip_runtime.h>

constexpr int N  = 100000;
constexpr int E  = 1600000;
constexpr int IN = 128, HID = 64, OUTC = 32;

// ---- bf16 helpers (manual, RNE) ----
__device__ __forceinline__ unsigned short f2bf(float f) {
    union { float f; unsigned int u; } v; v.f = f;
    unsigned int u = v.u;
    unsigned int r = (u + 0x7fffu + ((u >> 16) & 1u)) >> 16;
    return (unsigned short)r;
}
__device__ __forceinline__ float bf2f(unsigned short h) {
    union { unsigned int u; float f; } v; v.u = ((unsigned int)h) << 16;
    return v.f;
}

// ---------------- degree count (int atomics) ----------------
__global__ void k_deg(const int* __restrict__ dst, int* __restrict__ deg) {
    int t = blockIdx.x * blockDim.x + threadIdx.x;
    if (t < E) atomicAdd(&deg[dst[t]], 1);
}

// ---------------- scan stage 1: per-block exclusive scan + dinv ----------------
__global__ void k_scan1(const int* __restrict__ deg, int* __restrict__ offs,
                        int* __restrict__ partials, float* __restrict__ dinv) {
    __shared__ int sb[256];
    int t = threadIdx.x, g = blockIdx.x * 256 + t;
    int v = (g < N) ? deg[g] : 0;
    if (g < N) dinv[g] = rsqrtf((float)v + 1.0f);   // +1 self loop
    sb[t] = v; __syncthreads();
    for (int off = 1; off < 256; off <<= 1) {
        int x = (t >= off) ? sb[t - off] : 0;
        __syncthreads();
        sb[t] += x;
        __syncthreads();
    }
    if (g < N) offs[g] = sb[t] - v;                 // local exclusive
    if (t == 255) partials[blockIdx.x] = sb[255];
}

// ---------------- scan stage 2: scan the 391 block totals ----------------
__global__ void k_scan2(int* __restrict__ partials, int nb) {
    __shared__ int sb[512];
    int t = threadIdx.x;
    int v = (t < nb) ? partials[t] : 0;
    sb[t] = v; __syncthreads();
    for (int off = 1; off < 512; off <<= 1) {
        int x = (t >= off) ? sb[t - off] : 0;
        __syncthreads();
        sb[t] += x;
        __syncthreads();
    }
    if (t < nb) partials[t] = sb[t] - v;            // exclusive
}

// ---------------- scan stage 3: add block offsets, init cursor ----------------
__global__ void k_scan3(int* __restrict__ offs, const int* __restrict__ partials,
                        int* __restrict__ cursor) {
    int g = blockIdx.x * 256 + threadIdx.x;
    if (g < N) {
        int o = offs[g] + partials[blockIdx.x];
        offs[g] = o;
        cursor[g] = o;
    } else if (g == N) {
        offs[N] = E;
    }
}

// ---------------- CSR fill ----------------
__global__ void k_fill(const int* __restrict__ src, const int* __restrict__ dst,
                       int* __restrict__ cursor, int* __restrict__ csr) {
    int e = blockIdx.x * blockDim.x + threadIdx.x;
    if (e < E) {
        int d = dst[e];
        int pos = atomicAdd(&cursor[d], 1);
        csr[pos] = src[e];
    }
}

// ---------------- GEMM1: H = bf16(X @ W1)  (N x 128 @ 128 x 64) ----------------
__global__ __launch_bounds__(256) void k_gemm1(const float* __restrict__ X,
                                               const float* __restrict__ W,
                                               unsigned short* __restrict__ H) {
    constexpr int R  = 32;
    constexpr int XS = IN + 4;
    __shared__ float ws[IN * HID];             // 32 KB
    __shared__ float xs[R * XS];
    const int t    = threadIdx.x;
    const int row0 = blockIdx.x * R;

    for (int i = t; i < IN * HID / 4; i += 256)
        ((float4*)ws)[i] = ((const float4*)W)[i];
    for (int i = t; i < R * IN / 4; i += 256) {
        int r = i / (IN / 4), k4 = i % (IN / 4);
        *(float4*)&xs[r * XS + k4 * 4] =
            ((const float4*)(X + (size_t)(row0 + r) * IN))[k4];
    }
    __syncthreads();

    const int col0 = (t & 15) * 4;
    const int r0   = (t >> 4) * 2;
    float4 a0 = {0, 0, 0, 0}, a1 = {0, 0, 0, 0};
    for (int k = 0; k < IN; ++k) {
        float4 w = *(const float4*)&ws[k * HID + col0];
        float x0 = xs[r0 * XS + k];
        float x1 = xs[(r0 + 1) * XS + k];
        a0.x += x0 * w.x; a0.y += x0 * w.y; a0.z += x0 * w.z; a0.w += x0 * w.w;
        a1.x += x1 * w.x; a1.y += x1 * w.y; a1.z += x1 * w.z; a1.w += x1 * w.w;
    }
    ushort4 p0 = {f2bf(a0.x), f2bf(a0.y), f2bf(a0.z), f2bf(a0.w)};
    ushort4 p1 = {f2bf(a1.x), f2bf(a1.y), f2bf(a1.z), f2bf(a1.w)};
    *(ushort4*)(H + (size_t)(row0 + r0) * HID + col0)       = p0;
    *(ushort4*)(H + (size_t)(row0 + r0 + 1) * HID + col0)   = p1;
}

// ---------------- gather1: O1 = relu(dinv[d]*(Σ dinv[s]H[s] + dinv[d]H[d]) + b1) ----------------
__global__ __launch_bounds__(256) void k_gather1(const int* __restrict__ offs,
                                                 const int* __restrict__ csr,
                                                 const float* __restrict__ dinv,
                                                 const unsigned short* __restrict__ H,
                                                 const float* __restrict__ b,
                                                 float* __restrict__ O1) {
    const int c    = threadIdx.x & 63;
    const int node = blockIdx.x * 4 + (threadIdx.x >> 6);   // N % 4 == 0
    const float dn = dinv[node];
    float acc = dn * bf2f(H[(size_t)node * HID + c]);       // self loop
    int j   = offs[node];
    int end = offs[node + 1];
    for (; j + 1 < end; j += 2) {
        int s0 = csr[j], s1 = csr[j + 1];
        float d0 = dinv[s0], d1 = dinv[s1];
        float h0 = bf2f(H[(size_t)s0 * HID + c]);
        float h1 = bf2f(H[(size_t)s1 * HID + c]);
        acc += d0 * h0;
        acc += d1 * h1;
    }
    if (j < end) {
        int s = csr[j];
        acc += dinv[s] * bf2f(H[(size_t)s * HID + c]);
    }
    O1[(size_t)node * HID + c] = fmaxf(acc * dn + b[c], 0.0f);   // fused relu
}

// ---------------- GEMM2: H2 = bf16(O1 @ W2)  (N x 64 @ 64 x 32), O1 pre-relu'd ----------------
__global__ __launch_bounds__(256) void k_gemm2(const float* __restrict__ O1,
                                               const float* __restrict__ W,
                                               unsigned short* __restrict__ H2) {
    constexpr int R  = 32;
    constexpr int XS = HID + 4;
    __shared__ float ws[HID * OUTC];
    __shared__ float xs[R * XS];
    const int t    = threadIdx.x;
    const int row0 = blockIdx.x * R;

    for (int i = t; i < HID * OUTC / 4; i += 256)
        ((float4*)ws)[i] = ((const float4*)W)[i];
    for (int i = t; i < R * HID / 4; i += 256) {
        int r = i / (HID / 4), k4 = i % (HID / 4);
        *(float4*)&xs[r * XS + k4 * 4] =
            ((const float4*)(O1 + (size_t)(row0 + r) * HID))[k4];
    }
    __syncthreads();

    const int col0 = (t & 7) * 4;
    const int r    = t >> 3;
    float4 a = {0, 0, 0, 0};
    for (int k = 0; k < HID; ++k) {
        float4 w = *(const float4*)&ws[k * OUTC + col0];
        float x  = xs[r * XS + k];
        a.x += x * w.x; a.y += x * w.y; a.z += x * w.z; a.w += x * w.w;
    }
    ushort4 p = {f2bf(a.x), f2bf(a.y), f2bf(a.z), f2bf(a.w)};
    *(ushort4*)(H2 + (size_t)(row0 + r) * OUTC + col0) = p;
}

// ---------------- gather2: out = dinv[d]*(Σ dinv[s]H2[s] + dinv[d]H2[d]) + b2 ----------------
// wave per node; lane halves process alternating edges; combine via shfl.
__global__ __launch_bounds__(256) void k_gather2(const int* __restrict__ offs,
                                                 const int* __restrict__ csr,
                                                 const float* __restrict__ dinv,
                                                 const unsigned short* __restrict__ H2,
                                                 const float* __restrict__ b,
                                                 float* __restrict__ out) {
    const int lane = threadIdx.x & 63;
    const int c    = lane & 31;
    const int half = lane >> 5;
    const int node = blockIdx.x * 4 + (threadIdx.x >> 6);
    const float dn = dinv[node];
    float acc = (half == 0) ? dn * bf2f(H2[(size_t)node * OUTC + c]) : 0.0f;
    int beg = offs[node], end = offs[node + 1];
    for (int j = beg + half; j < end; j += 2) {
        int s = csr[j];
        acc += dinv[s] * bf2f(H2[(size_t)s * OUTC + c]);
    }
    acc += __shfl_down(acc, 32, 64);
    if (half == 0)
        out[(size_t)node * OUTC + c] = acc * dn + b[c];
}

extern "C" void kernel_launch(void* const* d_in, const int* in_sizes, int n_in,
                              void* d_out, int out_size, void* d_ws, size_t ws_size,
                              hipStream_t stream) {
    const float* x   = (const float*)d_in[0];
    const int*   ei  = (const int*)d_in[1];
    const float* W1  = (const float*)d_in[2];
    const float* b1  = (const float*)d_in[3];
    const float* W2  = (const float*)d_in[4];
    const float* b2  = (const float*)d_in[5];
    float*       out = (float*)d_out;

    const int* srcp = ei;
    const int* dstp = ei + E;

    char* ws = (char*)d_ws;
    // layout (bytes):
    int*            deg      = (int*)(ws + 0);                  // 400 KB
    float*          dinv     = (float*)(ws + (512u << 10));     // 400 KB
    int*            offs     = (int*)(ws + (1u << 20));         // 400 KB (+4)
    int*            cursor   = (int*)(ws + (1536u << 10));      // 400 KB
    int*            partials = (int*)(ws + (1960u << 10));      // 2 KB
    int*            csr      = (int*)(ws + (2u << 20));         // 6.4 MB
    unsigned short* H        = (unsigned short*)(ws + (8704u << 10));  // 12.8 MB
    float*          O1       = (float*)(ws + (22016u << 10));   // 25.6 MB -> ends ~47.1 MB
    unsigned short* H2       = H;                               // reuse: H dead after gather1

    const int nb = (N + 255) / 256;   // 391

    hipMemsetAsync(deg, 0, N * sizeof(int), stream);
    k_deg<<<(E + 255) / 256, 256, 0, stream>>>(dstp, deg);
    k_scan1<<<nb, 256, 0, stream>>>(deg, offs, partials, dinv);
    k_scan2<<<1, 512, 0, stream>>>(partials, nb);
    k_scan3<<<nb, 256, 0, stream>>>(offs, partials, cursor);
    k_fill<<<(E + 255) / 256, 256, 0, stream>>>(srcp, dstp, cursor, csr);

    k_gemm1<<<N / 32, 256, 0, stream>>>(x, W1, H);
    k_gather1<<<N / 4, 256, 0, stream>>>(offs, csr, dinv, H, b1, O1);
    k_gemm2<<<N / 32, 256, 0, stream>>>(O1, W2, H2);
    k_gather2<<<N / 4, 256, 0, stream>>>(offs, csr, dinv, H2, b2, out);
}

// Round 3
// 466.280 us; speedup vs baseline: 1.6220x; 1.0869x over previous
//
#include <hip/hip_runtime.h>

constexpr int N  = 100000;
constexpr int E  = 1600000;
constexpr int IN = 128, HID = 64, OUTC = 32;

// ---- bf16 helpers (manual, RNE) ----
__device__ __forceinline__ unsigned short f2bf(float f) {
    union { float f; unsigned int u; } v; v.f = f;
    unsigned int u = v.u;
    unsigned int r = (u + 0x7fffu + ((u >> 16) & 1u)) >> 16;
    return (unsigned short)r;
}
__device__ __forceinline__ float bf2f(unsigned short h) {
    union { unsigned int u; float f; } v; v.u = ((unsigned int)h) << 16;
    return v.f;
}

// ---------------- degree count (int atomics; 4B-granular memory-side) ----------------
__global__ void k_deg(const int* __restrict__ dst, int* __restrict__ deg) {
    int t = blockIdx.x * blockDim.x + threadIdx.x;
    if (t < E) atomicAdd(&deg[dst[t]], 1);
}

// ---------------- scan stage 1: per-block exclusive scan + dinv ----------------
__global__ void k_scan1(const int* __restrict__ deg, int* __restrict__ offs,
                        int* __restrict__ partials, float* __restrict__ dinv) {
    __shared__ int sb[256];
    int t = threadIdx.x, g = blockIdx.x * 256 + t;
    int v = (g < N) ? deg[g] : 0;
    if (g < N) dinv[g] = rsqrtf((float)v + 1.0f);   // +1 self loop
    sb[t] = v; __syncthreads();
    for (int off = 1; off < 256; off <<= 1) {
        int x = (t >= off) ? sb[t - off] : 0;
        __syncthreads();
        sb[t] += x;
        __syncthreads();
    }
    if (g < N) offs[g] = sb[t] - v;                 // local exclusive
    if (t == 255) partials[blockIdx.x] = sb[255];
}

// ---------------- scan stage 2: scan the 391 block totals ----------------
__global__ void k_scan2(int* __restrict__ partials, int nb) {
    __shared__ int sb[512];
    int t = threadIdx.x;
    int v = (t < nb) ? partials[t] : 0;
    sb[t] = v; __syncthreads();
    for (int off = 1; off < 512; off <<= 1) {
        int x = (t >= off) ? sb[t - off] : 0;
        __syncthreads();
        sb[t] += x;
        __syncthreads();
    }
    if (t < nb) partials[t] = sb[t] - v;            // exclusive
}

// ---------------- scan stage 3: add block offsets, init cursor ----------------
__global__ void k_scan3(int* __restrict__ offs, const int* __restrict__ partials,
                        int* __restrict__ cursor) {
    int g = blockIdx.x * 256 + threadIdx.x;
    if (g < N) {
        int o = offs[g] + partials[blockIdx.x];
        offs[g] = o;
        cursor[g] = o;
    } else if (g == N) {
        offs[N] = E;
    }
}

// ---------------- CSR fill, phased sweeps for write locality ----------------
// Pass s handles only dst in [s*RANGE, (s+1)*RANGE): active csr window ~800 KB
// stays L2-resident so 64B lines coalesce their ~16 entries before writeback.
// Edge list (12.8 MB) is L3-resident after pass 0 -> re-reads are cheap.
__global__ __launch_bounds__(256) void k_fill_swept(const int* __restrict__ src,
                                                    const int* __restrict__ dst,
                                                    int* __restrict__ cursor,
                                                    int* __restrict__ csr) {
    constexpr int SWEEPS = 8;
    constexpr int RANGE  = (N + SWEEPS - 1) / SWEEPS;   // 12500
    const int nthreads = gridDim.x * blockDim.x;
    const int tid = blockIdx.x * blockDim.x + threadIdx.x;
    for (int s = 0; s < SWEEPS; ++s) {
        const int lo = s * RANGE, hi = lo + RANGE;
        for (int e = tid; e < E; e += nthreads) {
            int d = dst[e];
            if (d >= lo && d < hi) {
                int pos = atomicAdd(&cursor[d], 1);
                csr[pos] = src[e];
            }
        }
    }
}

// ---------------- GEMM1: H = bf16(X @ W1)  (N x 128 @ 128 x 64) ----------------
__global__ __launch_bounds__(256) void k_gemm1(const float* __restrict__ X,
                                               const float* __restrict__ W,
                                               unsigned short* __restrict__ H) {
    constexpr int R  = 32;
    constexpr int XS = IN + 4;
    __shared__ float ws[IN * HID];             // 32 KB
    __shared__ float xs[R * XS];
    const int t    = threadIdx.x;
    const int row0 = blockIdx.x * R;

    for (int i = t; i < IN * HID / 4; i += 256)
        ((float4*)ws)[i] = ((const float4*)W)[i];
    for (int i = t; i < R * IN / 4; i += 256) {
        int r = i / (IN / 4), k4 = i % (IN / 4);
        *(float4*)&xs[r * XS + k4 * 4] =
            ((const float4*)(X + (size_t)(row0 + r) * IN))[k4];
    }
    __syncthreads();

    const int col0 = (t & 15) * 4;
    const int r0   = (t >> 4) * 2;
    float4 a0 = {0, 0, 0, 0}, a1 = {0, 0, 0, 0};
    for (int k = 0; k < IN; ++k) {
        float4 w = *(const float4*)&ws[k * HID + col0];
        float x0 = xs[r0 * XS + k];
        float x1 = xs[(r0 + 1) * XS + k];
        a0.x += x0 * w.x; a0.y += x0 * w.y; a0.z += x0 * w.z; a0.w += x0 * w.w;
        a1.x += x1 * w.x; a1.y += x1 * w.y; a1.z += x1 * w.z; a1.w += x1 * w.w;
    }
    ushort4 p0 = {f2bf(a0.x), f2bf(a0.y), f2bf(a0.z), f2bf(a0.w)};
    ushort4 p1 = {f2bf(a1.x), f2bf(a1.y), f2bf(a1.z), f2bf(a1.w)};
    *(ushort4*)(H + (size_t)(row0 + r0) * HID + col0)       = p0;
    *(ushort4*)(H + (size_t)(row0 + r0 + 1) * HID + col0)   = p1;
}

// ---------------- gather1: O1 = relu(dinv[d]*(Σ dinv[s]H[s] + dinv[d]H[d]) + b1) ----------------
__global__ __launch_bounds__(256) void k_gather1(const int* __restrict__ offs,
                                                 const int* __restrict__ csr,
                                                 const float* __restrict__ dinv,
                                                 const unsigned short* __restrict__ H,
                                                 const float* __restrict__ b,
                                                 float* __restrict__ O1) {
    const int c    = threadIdx.x & 63;
    const int node = blockIdx.x * 4 + (threadIdx.x >> 6);   // N % 4 == 0
    const float dn = dinv[node];
    float acc = dn * bf2f(H[(size_t)node * HID + c]);       // self loop
    int j   = offs[node];
    int end = offs[node + 1];
    for (; j + 1 < end; j += 2) {
        int s0 = csr[j], s1 = csr[j + 1];
        float d0 = dinv[s0], d1 = dinv[s1];
        float h0 = bf2f(H[(size_t)s0 * HID + c]);
        float h1 = bf2f(H[(size_t)s1 * HID + c]);
        acc += d0 * h0;
        acc += d1 * h1;
    }
    if (j < end) {
        int s = csr[j];
        acc += dinv[s] * bf2f(H[(size_t)s * HID + c]);
    }
    O1[(size_t)node * HID + c] = fmaxf(acc * dn + b[c], 0.0f);   // fused relu
}

// ---------------- GEMM2: H2 = bf16(O1 @ W2)  (N x 64 @ 64 x 32), O1 pre-relu'd ----------------
__global__ __launch_bounds__(256) void k_gemm2(const float* __restrict__ O1,
                                               const float* __restrict__ W,
                                               unsigned short* __restrict__ H2) {
    constexpr int R  = 32;
    constexpr int XS = HID + 4;
    __shared__ float ws[HID * OUTC];
    __shared__ float xs[R * XS];
    const int t    = threadIdx.x;
    const int row0 = blockIdx.x * R;

    for (int i = t; i < HID * OUTC / 4; i += 256)
        ((float4*)ws)[i] = ((const float4*)W)[i];
    for (int i = t; i < R * HID / 4; i += 256) {
        int r = i / (HID / 4), k4 = i % (HID / 4);
        *(float4*)&xs[r * XS + k4 * 4] =
            ((const float4*)(O1 + (size_t)(row0 + r) * HID))[k4];
    }
    __syncthreads();

    const int col0 = (t & 7) * 4;
    const int r    = t >> 3;
    float4 a = {0, 0, 0, 0};
    for (int k = 0; k < HID; ++k) {
        float4 w = *(const float4*)&ws[k * OUTC + col0];
        float x  = xs[r * XS + k];
        a.x += x * w.x; a.y += x * w.y; a.z += x * w.z; a.w += x * w.w;
    }
    ushort4 p = {f2bf(a.x), f2bf(a.y), f2bf(a.z), f2bf(a.w)};
    *(ushort4*)(H2 + (size_t)(row0 + r) * OUTC + col0) = p;
}

// ---------------- gather2: out = dinv[d]*(Σ dinv[s]H2[s] + dinv[d]H2[d]) + b2 ----------------
__global__ __launch_bounds__(256) void k_gather2(const int* __restrict__ offs,
                                                 const int* __restrict__ csr,
                                                 const float* __restrict__ dinv,
                                                 const unsigned short* __restrict__ H2,
                                                 const float* __restrict__ b,
                                                 float* __restrict__ out) {
    const int lane = threadIdx.x & 63;
    const int c    = lane & 31;
    const int half = lane >> 5;
    const int node = blockIdx.x * 4 + (threadIdx.x >> 6);
    const float dn = dinv[node];
    float acc = (half == 0) ? dn * bf2f(H2[(size_t)node * OUTC + c]) : 0.0f;
    int beg = offs[node], end = offs[node + 1];
    for (int j = beg + half; j < end; j += 2) {
        int s = csr[j];
        acc += dinv[s] * bf2f(H2[(size_t)s * OUTC + c]);
    }
    acc += __shfl_down(acc, 32, 64);
    if (half == 0)
        out[(size_t)node * OUTC + c] = acc * dn + b[c];
}

extern "C" void kernel_launch(void* const* d_in, const int* in_sizes, int n_in,
                              void* d_out, int out_size, void* d_ws, size_t ws_size,
                              hipStream_t stream) {
    const float* x   = (const float*)d_in[0];
    const int*   ei  = (const int*)d_in[1];
    const float* W1  = (const float*)d_in[2];
    const float* b1  = (const float*)d_in[3];
    const float* W2  = (const float*)d_in[4];
    const float* b2  = (const float*)d_in[5];
    float*       out = (float*)d_out;

    const int* srcp = ei;
    const int* dstp = ei + E;

    char* ws = (char*)d_ws;
    int*            deg      = (int*)(ws + 0);                  // 400 KB
    float*          dinv     = (float*)(ws + (512u << 10));     // 400 KB
    int*            offs     = (int*)(ws + (1u << 20));         // 400 KB (+4)
    int*            cursor   = (int*)(ws + (1536u << 10));      // 400 KB
    int*            partials = (int*)(ws + (1960u << 10));      // 2 KB
    int*            csr      = (int*)(ws + (2u << 20));         // 6.4 MB
    unsigned short* H        = (unsigned short*)(ws + (8704u << 10));  // 12.8 MB
    float*          O1       = (float*)(ws + (22016u << 10));   // 25.6 MB -> ends ~47.1 MB
    unsigned short* H2       = H;                               // reuse: H dead after gather1

    const int nb = (N + 255) / 256;   // 391

    hipMemsetAsync(deg, 0, N * sizeof(int), stream);
    k_deg<<<(E + 255) / 256, 256, 0, stream>>>(dstp, deg);
    k_scan1<<<nb, 256, 0, stream>>>(deg, offs, partials, dinv);
    k_scan2<<<1, 512, 0, stream>>>(partials, nb);
    k_scan3<<<nb, 256, 0, stream>>>(offs, partials, cursor);
    // near-persistent grid: 2048 blocks x 256 thr -> co-resident, sweeps stay in phase
    k_fill_swept<<<2048, 256, 0, stream>>>(srcp, dstp, cursor, csr);

    k_gemm1<<<N / 32, 256, 0, stream>>>(x, W1, H);
    k_gather1<<<N / 4, 256, 0, stream>>>(offs, csr, dinv, H, b1, O1);
    k_gemm2<<<N / 32, 256, 0, stream>>>(O1, W2, H2);
    k_gather2<<<N / 4, 256, 0, stream>>>(offs, csr, dinv, H2, b2, out);
}

// Round 4
// 406.003 us; speedup vs baseline: 1.8628x; 1.1485x over previous
//
#include <hip/hip_runtime.h>

constexpr int N  = 100000;
constexpr int E  = 1600000;
constexpr int IN = 128, HID = 64, OUTC = 32;

// ---- bf16 helpers (manual, RNE) ----
__device__ __forceinline__ unsigned short f2bf(float f) {
    union { float f; unsigned int u; } v; v.f = f;
    unsigned int u = v.u;
    unsigned int r = (u + 0x7fffu + ((u >> 16) & 1u)) >> 16;
    return (unsigned short)r;
}
__device__ __forceinline__ float bf2f(unsigned short h) {
    union { unsigned int u; float f; } v; v.u = ((unsigned int)h) << 16;
    return v.f;
}

// ---------------- degree count (int atomics; 4B-granular memory-side) ----------------
__global__ void k_deg(const int* __restrict__ dst, int* __restrict__ deg) {
    int t = blockIdx.x * blockDim.x + threadIdx.x;
    if (t < E) atomicAdd(&deg[dst[t]], 1);
}

// ---------------- scan stage 1: per-block exclusive scan + dinv ----------------
__global__ void k_scan1(const int* __restrict__ deg, int* __restrict__ offs,
                        int* __restrict__ partials, float* __restrict__ dinv) {
    __shared__ int sb[256];
    int t = threadIdx.x, g = blockIdx.x * 256 + t;
    int v = (g < N) ? deg[g] : 0;
    if (g < N) dinv[g] = rsqrtf((float)v + 1.0f);   // +1 self loop
    sb[t] = v; __syncthreads();
    for (int off = 1; off < 256; off <<= 1) {
        int x = (t >= off) ? sb[t - off] : 0;
        __syncthreads();
        sb[t] += x;
        __syncthreads();
    }
    if (g < N) offs[g] = sb[t] - v;                 // local exclusive
    if (t == 255) partials[blockIdx.x] = sb[255];
}

// ---------------- scan stage 2: scan the 391 block totals ----------------
__global__ void k_scan2(int* __restrict__ partials, int nb) {
    __shared__ int sb[512];
    int t = threadIdx.x;
    int v = (t < nb) ? partials[t] : 0;
    sb[t] = v; __syncthreads();
    for (int off = 1; off < 512; off <<= 1) {
        int x = (t >= off) ? sb[t - off] : 0;
        __syncthreads();
        sb[t] += x;
        __syncthreads();
    }
    if (t < nb) partials[t] = sb[t] - v;            // exclusive
}

// ---------------- scan stage 3: add block offsets, init cursor ----------------
__global__ void k_scan3(int* __restrict__ offs, const int* __restrict__ partials,
                        int* __restrict__ cursor) {
    int g = blockIdx.x * 256 + threadIdx.x;
    if (g < N) {
        int o = offs[g] + partials[blockIdx.x];
        offs[g] = o;
        cursor[g] = o;
    } else if (g == N) {
        offs[N] = E;
    }
}

// ---------------- CSR fill, phased sweeps for write locality ----------------
__global__ __launch_bounds__(256) void k_fill_swept(const int* __restrict__ src,
                                                    const int* __restrict__ dst,
                                                    int* __restrict__ cursor,
                                                    int* __restrict__ csr) {
    constexpr int SWEEPS = 8;
    constexpr int RANGE  = (N + SWEEPS - 1) / SWEEPS;   // 12500
    const int nthreads = gridDim.x * blockDim.x;
    const int tid = blockIdx.x * blockDim.x + threadIdx.x;
    for (int s = 0; s < SWEEPS; ++s) {
        const int lo = s * RANGE, hi = lo + RANGE;
        for (int e = tid; e < E; e += nthreads) {
            int d = dst[e];
            if (d >= lo && d < hi) {
                int pos = atomicAdd(&cursor[d], 1);
                csr[pos] = src[e];
            }
        }
    }
}

// ---------------- GEMM1: Hs = bf16(dinv[row] * (X @ W1)) ----------------
__global__ __launch_bounds__(256) void k_gemm1(const float* __restrict__ X,
                                               const float* __restrict__ W,
                                               const float* __restrict__ dinv,
                                               unsigned short* __restrict__ Hs) {
    constexpr int R  = 32;
    constexpr int XS = IN + 4;
    __shared__ float ws[IN * HID];             // 32 KB
    __shared__ float xs[R * XS];
    const int t    = threadIdx.x;
    const int row0 = blockIdx.x * R;

    for (int i = t; i < IN * HID / 4; i += 256)
        ((float4*)ws)[i] = ((const float4*)W)[i];
    for (int i = t; i < R * IN / 4; i += 256) {
        int r = i / (IN / 4), k4 = i % (IN / 4);
        *(float4*)&xs[r * XS + k4 * 4] =
            ((const float4*)(X + (size_t)(row0 + r) * IN))[k4];
    }
    __syncthreads();

    const int col0 = (t & 15) * 4;
    const int r0   = (t >> 4) * 2;
    float4 a0 = {0, 0, 0, 0}, a1 = {0, 0, 0, 0};
    for (int k = 0; k < IN; ++k) {
        float4 w = *(const float4*)&ws[k * HID + col0];
        float x0 = xs[r0 * XS + k];
        float x1 = xs[(r0 + 1) * XS + k];
        a0.x += x0 * w.x; a0.y += x0 * w.y; a0.z += x0 * w.z; a0.w += x0 * w.w;
        a1.x += x1 * w.x; a1.y += x1 * w.y; a1.z += x1 * w.z; a1.w += x1 * w.w;
    }
    const float d0 = dinv[row0 + r0];
    const float d1 = dinv[row0 + r0 + 1];
    ushort4 p0 = {f2bf(a0.x * d0), f2bf(a0.y * d0), f2bf(a0.z * d0), f2bf(a0.w * d0)};
    ushort4 p1 = {f2bf(a1.x * d1), f2bf(a1.y * d1), f2bf(a1.z * d1), f2bf(a1.w * d1)};
    *(ushort4*)(Hs + (size_t)(row0 + r0) * HID + col0)       = p0;
    *(ushort4*)(Hs + (size_t)(row0 + r0 + 1) * HID + col0)   = p1;
}

// ---------------- gather1: O1 = relu(dinv[d]*(Hs[d] + Σ Hs[s]) + b1) ----------------
// Hs rows pre-scaled by dinv -> pure load+add inner loop; unroll x4, 2 acc chains.
__global__ __launch_bounds__(256) void k_gather1(const int* __restrict__ offs,
                                                 const int* __restrict__ csr,
                                                 const float* __restrict__ dinv,
                                                 const unsigned short* __restrict__ Hs,
                                                 const float* __restrict__ b,
                                                 float* __restrict__ O1) {
    const int c    = threadIdx.x & 63;
    const int node = blockIdx.x * 4 + (threadIdx.x >> 6);   // N % 4 == 0
    float acc0 = bf2f(Hs[(size_t)node * HID + c]);          // self loop (pre-scaled)
    float acc1 = 0.0f;
    int j   = offs[node];
    int end = offs[node + 1];
    for (; j + 3 < end; j += 4) {
        int s0 = csr[j], s1 = csr[j + 1], s2 = csr[j + 2], s3 = csr[j + 3];
        float h0 = bf2f(Hs[(size_t)s0 * HID + c]);
        float h1 = bf2f(Hs[(size_t)s1 * HID + c]);
        float h2 = bf2f(Hs[(size_t)s2 * HID + c]);
        float h3 = bf2f(Hs[(size_t)s3 * HID + c]);
        acc0 += h0 + h2;
        acc1 += h1 + h3;
    }
    for (; j < end; ++j)
        acc0 += bf2f(Hs[(size_t)csr[j] * HID + c]);
    const float dn = dinv[node];
    O1[(size_t)node * HID + c] = fmaxf((acc0 + acc1) * dn + b[c], 0.0f);   // fused relu
}

// ---------------- GEMM2: H2s = bf16(dinv[row] * (O1 @ W2)), O1 pre-relu'd ----------------
__global__ __launch_bounds__(256) void k_gemm2(const float* __restrict__ O1,
                                               const float* __restrict__ W,
                                               const float* __restrict__ dinv,
                                               unsigned short* __restrict__ H2s) {
    constexpr int R  = 32;
    constexpr int XS = HID + 4;
    __shared__ float ws[HID * OUTC];
    __shared__ float xs[R * XS];
    const int t    = threadIdx.x;
    const int row0 = blockIdx.x * R;

    for (int i = t; i < HID * OUTC / 4; i += 256)
        ((float4*)ws)[i] = ((const float4*)W)[i];
    for (int i = t; i < R * HID / 4; i += 256) {
        int r = i / (HID / 4), k4 = i % (HID / 4);
        *(float4*)&xs[r * XS + k4 * 4] =
            ((const float4*)(O1 + (size_t)(row0 + r) * HID))[k4];
    }
    __syncthreads();

    const int col0 = (t & 7) * 4;
    const int r    = t >> 3;
    float4 a = {0, 0, 0, 0};
    for (int k = 0; k < HID; ++k) {
        float4 w = *(const float4*)&ws[k * OUTC + col0];
        float x  = xs[r * XS + k];
        a.x += x * w.x; a.y += x * w.y; a.z += x * w.z; a.w += x * w.w;
    }
    const float dd = dinv[row0 + r];
    ushort4 p = {f2bf(a.x * dd), f2bf(a.y * dd), f2bf(a.z * dd), f2bf(a.w * dd)};
    *(ushort4*)(H2s + (size_t)(row0 + r) * OUTC + col0) = p;
}

// ---------------- gather2: out = dinv[d]*(H2s[d] + Σ H2s[s]) + b2 ----------------
// half-wave per edge stream, unroll x4 per half (8 edges in flight per wave).
__global__ __launch_bounds__(256) void k_gather2(const int* __restrict__ offs,
                                                 const int* __restrict__ csr,
                                                 const float* __restrict__ dinv,
                                                 const unsigned short* __restrict__ H2s,
                                                 const float* __restrict__ b,
                                                 float* __restrict__ out) {
    const int lane = threadIdx.x & 63;
    const int c    = lane & 31;
    const int half = lane >> 5;
    const int node = blockIdx.x * 4 + (threadIdx.x >> 6);
    float acc0 = (half == 0) ? bf2f(H2s[(size_t)node * OUTC + c]) : 0.0f;
    float acc1 = 0.0f;
    const int end = offs[node + 1];
    int j = offs[node] + half;
    for (; j + 6 < end; j += 8) {
        int s0 = csr[j], s1 = csr[j + 2], s2 = csr[j + 4], s3 = csr[j + 6];
        float h0 = bf2f(H2s[(size_t)s0 * OUTC + c]);
        float h1 = bf2f(H2s[(size_t)s1 * OUTC + c]);
        float h2 = bf2f(H2s[(size_t)s2 * OUTC + c]);
        float h3 = bf2f(H2s[(size_t)s3 * OUTC + c]);
        acc0 += h0 + h2;
        acc1 += h1 + h3;
    }
    for (; j < end; j += 2)
        acc0 += bf2f(H2s[(size_t)csr[j] * OUTC + c]);
    float acc = acc0 + acc1;
    acc += __shfl_down(acc, 32, 64);
    if (half == 0)
        out[(size_t)node * OUTC + c] = acc * dinv[node] + b[c];
}

extern "C" void kernel_launch(void* const* d_in, const int* in_sizes, int n_in,
                              void* d_out, int out_size, void* d_ws, size_t ws_size,
                              hipStream_t stream) {
    const float* x   = (const float*)d_in[0];
    const int*   ei  = (const int*)d_in[1];
    const float* W1  = (const float*)d_in[2];
    const float* b1  = (const float*)d_in[3];
    const float* W2  = (const float*)d_in[4];
    const float* b2  = (const float*)d_in[5];
    float*       out = (float*)d_out;

    const int* srcp = ei;
    const int* dstp = ei + E;

    char* ws = (char*)d_ws;
    int*            deg      = (int*)(ws + 0);                  // 400 KB
    float*          dinv     = (float*)(ws + (512u << 10));     // 400 KB
    int*            offs     = (int*)(ws + (1u << 20));         // 400 KB (+4)
    int*            cursor   = (int*)(ws + (1536u << 10));      // 400 KB
    int*            partials = (int*)(ws + (1960u << 10));      // 2 KB
    int*            csr      = (int*)(ws + (2u << 20));         // 6.4 MB
    unsigned short* Hs       = (unsigned short*)(ws + (8704u << 10));  // 12.8 MB
    float*          O1       = (float*)(ws + (22016u << 10));   // 25.6 MB -> ends ~47.1 MB
    unsigned short* H2s      = Hs;                              // reuse: Hs dead after gather1

    const int nb = (N + 255) / 256;   // 391

    hipMemsetAsync(deg, 0, N * sizeof(int), stream);
    k_deg<<<(E + 255) / 256, 256, 0, stream>>>(dstp, deg);
    k_scan1<<<nb, 256, 0, stream>>>(deg, offs, partials, dinv);
    k_scan2<<<1, 512, 0, stream>>>(partials, nb);
    k_scan3<<<nb, 256, 0, stream>>>(offs, partials, cursor);
    k_fill_swept<<<2048, 256, 0, stream>>>(srcp, dstp, cursor, csr);

    k_gemm1<<<N / 32, 256, 0, stream>>>(x, W1, dinv, Hs);
    k_gather1<<<N / 4, 256, 0, stream>>>(offs, csr, dinv, Hs, b1, O1);
    k_gemm2<<<N / 32, 256, 0, stream>>>(O1, W2, dinv, H2s);
    k_gather2<<<N / 4, 256, 0, stream>>>(offs, csr, dinv, H2s, b2, out);
}

// Round 5
// 393.467 us; speedup vs baseline: 1.9222x; 1.0319x over previous
//
#include <hip/hip_runtime.h>

constexpr int N  = 100000;
constexpr int E  = 1600000;
constexpr int IN = 128, HID = 64, OUTC = 32;

// ---- bf16 helpers (manual, RNE) ----
__device__ __forceinline__ unsigned short f2bf(float f) {
    union { float f; unsigned int u; } v; v.f = f;
    unsigned int u = v.u;
    unsigned int r = (u + 0x7fffu + ((u >> 16) & 1u)) >> 16;
    return (unsigned short)r;
}
__device__ __forceinline__ float bf2f(unsigned short h) {
    union { unsigned int u; float f; } v; v.u = ((unsigned int)h) << 16;
    return v.f;
}

// ---------------- degree count (int atomics; 4B-granular memory-side) ----------------
__global__ void k_deg(const int* __restrict__ dst, int* __restrict__ deg) {
    int t = blockIdx.x * blockDim.x + threadIdx.x;
    if (t < E) atomicAdd(&deg[dst[t]], 1);
}

// ---------------- scan stage 1: per-block exclusive scan + dinv ----------------
__global__ void k_scan1(const int* __restrict__ deg, int* __restrict__ offs,
                        int* __restrict__ partials, float* __restrict__ dinv) {
    __shared__ int sb[256];
    int t = threadIdx.x, g = blockIdx.x * 256 + t;
    int v = (g < N) ? deg[g] : 0;
    if (g < N) dinv[g] = rsqrtf((float)v + 1.0f);   // +1 self loop
    sb[t] = v; __syncthreads();
    for (int off = 1; off < 256; off <<= 1) {
        int x = (t >= off) ? sb[t - off] : 0;
        __syncthreads();
        sb[t] += x;
        __syncthreads();
    }
    if (g < N) offs[g] = sb[t] - v;                 // local exclusive
    if (t == 255) partials[blockIdx.x] = sb[255];
}

// ---------------- scan stage 2: scan the 391 block totals ----------------
__global__ void k_scan2(int* __restrict__ partials, int nb) {
    __shared__ int sb[512];
    int t = threadIdx.x;
    int v = (t < nb) ? partials[t] : 0;
    sb[t] = v; __syncthreads();
    for (int off = 1; off < 512; off <<= 1) {
        int x = (t >= off) ? sb[t - off] : 0;
        __syncthreads();
        sb[t] += x;
        __syncthreads();
    }
    if (t < nb) partials[t] = sb[t] - v;            // exclusive
}

// ---------------- scan stage 3: add block offsets, init cursor ----------------
__global__ void k_scan3(int* __restrict__ offs, const int* __restrict__ partials,
                        int* __restrict__ cursor) {
    int g = blockIdx.x * 256 + threadIdx.x;
    if (g < N) {
        int o = offs[g] + partials[blockIdx.x];
        offs[g] = o;
        cursor[g] = o;
    } else if (g == N) {
        offs[N] = E;
    }
}

// ---------------- CSR fill, XCD-partitioned for write locality ----------------
// Block's XCD ~ blockIdx&7 (round-robin dispatch). Each XCD owns a 12500-node
// dst range: its 800 KB csr window is written ONLY from that XCD's L2, so 64B
// lines accumulate all ~16 entries before writeback (no cross-XCD partial
// lines). Each XCD-group re-scans the full dst stream; L3 absorbs re-reads.
__global__ __launch_bounds__(256) void k_fill_xcd(const int* __restrict__ src,
                                                  const int* __restrict__ dst,
                                                  int* __restrict__ cursor,
                                                  int* __restrict__ csr) {
    constexpr int NXCD  = 8;
    constexpr int RANGE = N / NXCD;                 // 12500
    const int xcd  = blockIdx.x & (NXCD - 1);
    const int lo   = xcd * RANGE, hi = lo + RANGE;
    const int sub  = (blockIdx.x >> 3) * 256 + threadIdx.x;
    const int nsub = (gridDim.x >> 3) * 256;
    for (int e = sub; e < E; e += nsub) {
        int d = dst[e];
        if (d >= lo && d < hi) {
            int pos = atomicAdd(&cursor[d], 1);
            csr[pos] = src[e];
        }
    }
}

// ---------------- GEMM1: Hs = bf16(dinv[row] * (X @ W1)) ----------------
__global__ __launch_bounds__(256) void k_gemm1(const float* __restrict__ X,
                                               const float* __restrict__ W,
                                               const float* __restrict__ dinv,
                                               unsigned short* __restrict__ Hs) {
    constexpr int R  = 32;
    constexpr int XS = IN + 4;
    __shared__ float ws[IN * HID];             // 32 KB
    __shared__ float xs[R * XS];
    const int t    = threadIdx.x;
    const int row0 = blockIdx.x * R;

    for (int i = t; i < IN * HID / 4; i += 256)
        ((float4*)ws)[i] = ((const float4*)W)[i];
    for (int i = t; i < R * IN / 4; i += 256) {
        int r = i / (IN / 4), k4 = i % (IN / 4);
        *(float4*)&xs[r * XS + k4 * 4] =
            ((const float4*)(X + (size_t)(row0 + r) * IN))[k4];
    }
    __syncthreads();

    const int col0 = (t & 15) * 4;
    const int r0   = (t >> 4) * 2;
    float4 a0 = {0, 0, 0, 0}, a1 = {0, 0, 0, 0};
    for (int k = 0; k < IN; ++k) {
        float4 w = *(const float4*)&ws[k * HID + col0];
        float x0 = xs[r0 * XS + k];
        float x1 = xs[(r0 + 1) * XS + k];
        a0.x += x0 * w.x; a0.y += x0 * w.y; a0.z += x0 * w.z; a0.w += x0 * w.w;
        a1.x += x1 * w.x; a1.y += x1 * w.y; a1.z += x1 * w.z; a1.w += x1 * w.w;
    }
    const float d0 = dinv[row0 + r0];
    const float d1 = dinv[row0 + r0 + 1];
    ushort4 p0 = {f2bf(a0.x * d0), f2bf(a0.y * d0), f2bf(a0.z * d0), f2bf(a0.w * d0)};
    ushort4 p1 = {f2bf(a1.x * d1), f2bf(a1.y * d1), f2bf(a1.z * d1), f2bf(a1.w * d1)};
    *(ushort4*)(Hs + (size_t)(row0 + r0) * HID + col0)       = p0;
    *(ushort4*)(Hs + (size_t)(row0 + r0 + 1) * HID + col0)   = p1;
}

// ---------------- gather1: O1 = relu(dinv[d]*(Hs[d] + Σ Hs[s]) + b1) ----------------
__global__ __launch_bounds__(256) void k_gather1(const int* __restrict__ offs,
                                                 const int* __restrict__ csr,
                                                 const float* __restrict__ dinv,
                                                 const unsigned short* __restrict__ Hs,
                                                 const float* __restrict__ b,
                                                 float* __restrict__ O1) {
    const int c    = threadIdx.x & 63;
    const int node = blockIdx.x * 4 + (threadIdx.x >> 6);   // N % 4 == 0
    float acc0 = bf2f(Hs[(size_t)node * HID + c]);          // self loop (pre-scaled)
    float acc1 = 0.0f;
    int j   = offs[node];
    int end = offs[node + 1];
    for (; j + 3 < end; j += 4) {
        int s0 = csr[j], s1 = csr[j + 1], s2 = csr[j + 2], s3 = csr[j + 3];
        float h0 = bf2f(Hs[(size_t)s0 * HID + c]);
        float h1 = bf2f(Hs[(size_t)s1 * HID + c]);
        float h2 = bf2f(Hs[(size_t)s2 * HID + c]);
        float h3 = bf2f(Hs[(size_t)s3 * HID + c]);
        acc0 += h0 + h2;
        acc1 += h1 + h3;
    }
    for (; j < end; ++j)
        acc0 += bf2f(Hs[(size_t)csr[j] * HID + c]);
    const float dn = dinv[node];
    O1[(size_t)node * HID + c] = fmaxf((acc0 + acc1) * dn + b[c], 0.0f);   // fused relu
}

// ---------------- GEMM2: H2s = bf16(dinv[row] * (O1 @ W2)), O1 pre-relu'd ----------------
__global__ __launch_bounds__(256) void k_gemm2(const float* __restrict__ O1,
                                               const float* __restrict__ W,
                                               const float* __restrict__ dinv,
                                               unsigned short* __restrict__ H2s) {
    constexpr int R  = 32;
    constexpr int XS = HID + 4;
    __shared__ float ws[HID * OUTC];
    __shared__ float xs[R * XS];
    const int t    = threadIdx.x;
    const int row0 = blockIdx.x * R;

    for (int i = t; i < HID * OUTC / 4; i += 256)
        ((float4*)ws)[i] = ((const float4*)W)[i];
    for (int i = t; i < R * HID / 4; i += 256) {
        int r = i / (HID / 4), k4 = i % (HID / 4);
        *(float4*)&xs[r * XS + k4 * 4] =
            ((const float4*)(O1 + (size_t)(row0 + r) * HID))[k4];
    }
    __syncthreads();

    const int col0 = (t & 7) * 4;
    const int r    = t >> 3;
    float4 a = {0, 0, 0, 0};
    for (int k = 0; k < HID; ++k) {
        float4 w = *(const float4*)&ws[k * OUTC + col0];
        float x  = xs[r * XS + k];
        a.x += x * w.x; a.y += x * w.y; a.z += x * w.z; a.w += x * w.w;
    }
    const float dd = dinv[row0 + r];
    ushort4 p = {f2bf(a.x * dd), f2bf(a.y * dd), f2bf(a.z * dd), f2bf(a.w * dd)};
    *(ushort4*)(H2s + (size_t)(row0 + r) * OUTC + col0) = p;
}

// ---------------- gather2: out = dinv[d]*(H2s[d] + Σ H2s[s]) + b2 ----------------
__global__ __launch_bounds__(256) void k_gather2(const int* __restrict__ offs,
                                                 const int* __restrict__ csr,
                                                 const float* __restrict__ dinv,
                                                 const unsigned short* __restrict__ H2s,
                                                 const float* __restrict__ b,
                                                 float* __restrict__ out) {
    const int lane = threadIdx.x & 63;
    const int c    = lane & 31;
    const int half = lane >> 5;
    const int node = blockIdx.x * 4 + (threadIdx.x >> 6);
    float acc0 = (half == 0) ? bf2f(H2s[(size_t)node * OUTC + c]) : 0.0f;
    float acc1 = 0.0f;
    const int end = offs[node + 1];
    int j = offs[node] + half;
    for (; j + 6 < end; j += 8) {
        int s0 = csr[j], s1 = csr[j + 2], s2 = csr[j + 4], s3 = csr[j + 6];
        float h0 = bf2f(H2s[(size_t)s0 * OUTC + c]);
        float h1 = bf2f(H2s[(size_t)s1 * OUTC + c]);
        float h2 = bf2f(H2s[(size_t)s2 * OUTC + c]);
        float h3 = bf2f(H2s[(size_t)s3 * OUTC + c]);
        acc0 += h0 + h2;
        acc1 += h1 + h3;
    }
    for (; j < end; j += 2)
        acc0 += bf2f(H2s[(size_t)csr[j] * OUTC + c]);
    float acc = acc0 + acc1;
    acc += __shfl_down(acc, 32, 64);
    if (half == 0)
        out[(size_t)node * OUTC + c] = acc * dinv[node] + b[c];
}

extern "C" void kernel_launch(void* const* d_in, const int* in_sizes, int n_in,
                              void* d_out, int out_size, void* d_ws, size_t ws_size,
                              hipStream_t stream) {
    const float* x   = (const float*)d_in[0];
    const int*   ei  = (const int*)d_in[1];
    const float* W1  = (const float*)d_in[2];
    const float* b1  = (const float*)d_in[3];
    const float* W2  = (const float*)d_in[4];
    const float* b2  = (const float*)d_in[5];
    float*       out = (float*)d_out;

    const int* srcp = ei;
    const int* dstp = ei + E;

    char* ws = (char*)d_ws;
    int*            deg      = (int*)(ws + 0);                  // 400 KB
    float*          dinv     = (float*)(ws + (512u << 10));     // 400 KB
    int*            offs     = (int*)(ws + (1u << 20));         // 400 KB (+4)
    int*            cursor   = (int*)(ws + (1536u << 10));      // 400 KB
    int*            partials = (int*)(ws + (1960u << 10));      // 2 KB
    int*            csr      = (int*)(ws + (2u << 20));         // 6.4 MB
    unsigned short* Hs       = (unsigned short*)(ws + (8704u << 10));  // 12.8 MB
    float*          O1       = (float*)(ws + (22016u << 10));   // 25.6 MB -> ends ~47.1 MB
    unsigned short* H2s      = Hs;                              // reuse: Hs dead after gather1

    const int nb = (N + 255) / 256;   // 391

    hipMemsetAsync(deg, 0, N * sizeof(int), stream);
    k_deg<<<(E + 255) / 256, 256, 0, stream>>>(dstp, deg);
    k_scan1<<<nb, 256, 0, stream>>>(deg, offs, partials, dinv);
    k_scan2<<<1, 512, 0, stream>>>(partials, nb);
    k_scan3<<<nb, 256, 0, stream>>>(offs, partials, cursor);
    // 2048 blocks x 256 thr = 8 blocks/CU (VGPR 8) -> fully co-resident
    k_fill_xcd<<<2048, 256, 0, stream>>>(srcp, dstp, cursor, csr);

    k_gemm1<<<N / 32, 256, 0, stream>>>(x, W1, dinv, Hs);
    k_gather1<<<N / 4, 256, 0, stream>>>(offs, csr, dinv, Hs, b1, O1);
    k_gemm2<<<N / 32, 256, 0, stream>>>(O1, W2, dinv, H2s);
    k_gather2<<<N / 4, 256, 0, stream>>>(offs, csr, dinv, H2s, b2, out);
}

// Round 6
// 305.696 us; speedup vs baseline: 2.4741x; 1.2871x over previous
//
#include <hip/hip_runtime.h>

constexpr int N  = 100000;
constexpr int E  = 1600000;
constexpr int IN = 128, HID = 64, OUTC = 32;

// coarse radix partition params
constexpr int SHIFT = 9;                       // 512 nodes per bucket
constexpr int NPB   = 1 << SHIFT;              // 512
constexpr int NB    = (N + NPB - 1) / NPB;     // 196 buckets
constexpr int CAP   = 16384;                   // LDS stage cap (mean 8163, sigma~90 -> unreachable)
constexpr int PB    = 256;                     // partition blocks
constexpr int CHUNK = E / PB;                  // 6250 (exact)

// ---- bf16 helpers (manual, RNE) ----
__device__ __forceinline__ unsigned short f2bf(float f) {
    union { float f; unsigned int u; } v; v.f = f;
    unsigned int u = v.u;
    unsigned int r = (u + 0x7fffu + ((u >> 16) & 1u)) >> 16;
    return (unsigned short)r;
}
__device__ __forceinline__ float bf2f(unsigned short h) {
    union { unsigned int u; float f; } v; v.u = ((unsigned int)h) << 16;
    return v.f;
}

// ---------------- coarse histogram: gcnt[b] = #edges with dst>>9 == b ----------------
__global__ __launch_bounds__(256) void k_hist(const int* __restrict__ dst,
                                              int* __restrict__ gcnt) {
    __shared__ int h[NB];
    for (int i = threadIdx.x; i < NB; i += 256) h[i] = 0;
    __syncthreads();
    const int tid = blockIdx.x * 256 + threadIdx.x, nt = gridDim.x * 256;
    for (int e = tid; e < E; e += nt) atomicAdd(&h[dst[e] >> SHIFT], 1);
    __syncthreads();
    for (int i = threadIdx.x; i < NB; i += 256)
        if (h[i]) atomicAdd(&gcnt[i], h[i]);
}

// ---------------- scan 196 bucket totals -> bases + reservation cursors ----------------
__global__ void k_bscan(const int* __restrict__ gcnt, int* __restrict__ base,
                        int* __restrict__ cursor) {
    __shared__ int sb[256];
    const int t = threadIdx.x;
    int v = (t < NB) ? gcnt[t] : 0;
    sb[t] = v; __syncthreads();
    for (int off = 1; off < 256; off <<= 1) {
        int x = (t >= off) ? sb[t - off] : 0;
        __syncthreads();
        sb[t] += x;
        __syncthreads();
    }
    if (t < NB) { int ex = sb[t] - v; base[t] = ex; cursor[t] = ex; }
    if (t == 0) base[NB] = E;
}

// ---------------- partition edges into coarse buckets (packed (dstLow<<17)|src) ----------------
// One global atomicAdd per (block,bucket); writes are ~128B contiguous runs.
__global__ __launch_bounds__(256) void k_part(const int* __restrict__ src,
                                              const int* __restrict__ dst,
                                              int* __restrict__ cursor,
                                              unsigned* __restrict__ packed) {
    __shared__ int lh[NB], lb[NB], lc[NB];
    const int t = threadIdx.x;
    const int beg = blockIdx.x * CHUNK, end = beg + CHUNK;
    for (int i = t; i < NB; i += 256) lh[i] = 0;
    __syncthreads();
    for (int e = beg + t; e < end; e += 256) atomicAdd(&lh[dst[e] >> SHIFT], 1);
    __syncthreads();
    for (int i = t; i < NB; i += 256) {
        lb[i] = lh[i] ? atomicAdd(&cursor[i], lh[i]) : 0;
        lc[i] = 0;
    }
    __syncthreads();
    for (int e = beg + t; e < end; e += 256) {
        int d = dst[e], b = d >> SHIFT;
        int idx = atomicAdd(&lc[b], 1);
        packed[lb[b] + idx] = ((unsigned)(d & (NPB - 1)) << 17) | (unsigned)src[e];
    }
}

// ---------------- per-bucket CSR build: offs + dinv + in-place sorted csr ----------------
// Block b owns nodes [b*512, ...) and packed[base..base+cnt). LDS count -> scan
// (gives offs and dinv) -> LDS scatter -> coalesced in-place flush (csr aliases
// packed: each block overwrites exactly its own segment after reading it).
__global__ __launch_bounds__(512) void k_build(const int* __restrict__ bbase,
                                               unsigned* __restrict__ packed,
                                               int* __restrict__ offs,
                                               float* __restrict__ dinv) {
    __shared__ int cnt[NPB];
    __shared__ unsigned stage[CAP];            // 64 KB
    const int t = threadIdx.x, b = blockIdx.x;
    const int base = bbase[b], cntE = bbase[b + 1] - base;
    const int node0 = b << SHIFT;
    cnt[t] = 0;
    __syncthreads();
    for (int i = t; i < cntE; i += 512) atomicAdd(&cnt[packed[base + i] >> 17], 1);
    __syncthreads();
    const int v = cnt[t];                      // this node's in-degree
    __syncthreads();
    for (int off = 1; off < NPB; off <<= 1) {  // Hillis-Steele inclusive scan
        int x = (t >= off) ? cnt[t - off] : 0;
        __syncthreads();
        cnt[t] += x;
        __syncthreads();
    }
    const int ex = cnt[t] - v;                 // exclusive, bucket-relative
    const int node = node0 + t;
    if (node < N) {
        offs[node] = base + ex;
        dinv[node] = rsqrtf((float)v + 1.0f);  // +1 self loop
    }
    if (node == N) offs[N] = E;
    __syncthreads();
    cnt[t] = ex;                               // reuse as scatter cursor
    __syncthreads();
    for (int i = t; i < cntE; i += 512) {
        unsigned p = packed[base + i];
        int idx = atomicAdd(&cnt[p >> 17], 1);
        if (idx < CAP) stage[idx] = p & 0x1FFFFu;   // src; CAP overflow statistically unreachable
    }
    __syncthreads();
    for (int i = t; i < cntE; i += 512)
        packed[base + i] = stage[i];           // in-place: csr == packed buffer
}

// ---------------- GEMM1: Hs = bf16(dinv[row] * (X @ W1)) ----------------
__global__ __launch_bounds__(256) void k_gemm1(const float* __restrict__ X,
                                               const float* __restrict__ W,
                                               const float* __restrict__ dinv,
                                               unsigned short* __restrict__ Hs) {
    constexpr int R  = 32;
    constexpr int XS = IN + 4;
    __shared__ float ws[IN * HID];             // 32 KB
    __shared__ float xs[R * XS];
    const int t    = threadIdx.x;
    const int row0 = blockIdx.x * R;

    for (int i = t; i < IN * HID / 4; i += 256)
        ((float4*)ws)[i] = ((const float4*)W)[i];
    for (int i = t; i < R * IN / 4; i += 256) {
        int r = i / (IN / 4), k4 = i % (IN / 4);
        *(float4*)&xs[r * XS + k4 * 4] =
            ((const float4*)(X + (size_t)(row0 + r) * IN))[k4];
    }
    __syncthreads();

    const int col0 = (t & 15) * 4;
    const int r0   = (t >> 4) * 2;
    float4 a0 = {0, 0, 0, 0}, a1 = {0, 0, 0, 0};
    for (int k = 0; k < IN; ++k) {
        float4 w = *(const float4*)&ws[k * HID + col0];
        float x0 = xs[r0 * XS + k];
        float x1 = xs[(r0 + 1) * XS + k];
        a0.x += x0 * w.x; a0.y += x0 * w.y; a0.z += x0 * w.z; a0.w += x0 * w.w;
        a1.x += x1 * w.x; a1.y += x1 * w.y; a1.z += x1 * w.z; a1.w += x1 * w.w;
    }
    const float d0 = dinv[row0 + r0];
    const float d1 = dinv[row0 + r0 + 1];
    ushort4 p0 = {f2bf(a0.x * d0), f2bf(a0.y * d0), f2bf(a0.z * d0), f2bf(a0.w * d0)};
    ushort4 p1 = {f2bf(a1.x * d1), f2bf(a1.y * d1), f2bf(a1.z * d1), f2bf(a1.w * d1)};
    *(ushort4*)(Hs + (size_t)(row0 + r0) * HID + col0)       = p0;
    *(ushort4*)(Hs + (size_t)(row0 + r0 + 1) * HID + col0)   = p1;
}

// ---------------- gather1: O1 = relu(dinv[d]*(Hs[d] + Σ Hs[s]) + b1) ----------------
__global__ __launch_bounds__(256) void k_gather1(const int* __restrict__ offs,
                                                 const int* __restrict__ csr,
                                                 const float* __restrict__ dinv,
                                                 const unsigned short* __restrict__ Hs,
                                                 const float* __restrict__ b,
                                                 float* __restrict__ O1) {
    const int c    = threadIdx.x & 63;
    const int node = blockIdx.x * 4 + (threadIdx.x >> 6);   // N % 4 == 0
    float acc0 = bf2f(Hs[(size_t)node * HID + c]);          // self loop (pre-scaled)
    float acc1 = 0.0f;
    int j   = offs[node];
    int end = offs[node + 1];
    for (; j + 3 < end; j += 4) {
        int s0 = csr[j], s1 = csr[j + 1], s2 = csr[j + 2], s3 = csr[j + 3];
        float h0 = bf2f(Hs[(size_t)s0 * HID + c]);
        float h1 = bf2f(Hs[(size_t)s1 * HID + c]);
        float h2 = bf2f(Hs[(size_t)s2 * HID + c]);
        float h3 = bf2f(Hs[(size_t)s3 * HID + c]);
        acc0 += h0 + h2;
        acc1 += h1 + h3;
    }
    for (; j < end; ++j)
        acc0 += bf2f(Hs[(size_t)csr[j] * HID + c]);
    const float dn = dinv[node];
    O1[(size_t)node * HID + c] = fmaxf((acc0 + acc1) * dn + b[c], 0.0f);   // fused relu
}

// ---------------- GEMM2: H2s = bf16(dinv[row] * (O1 @ W2)), O1 pre-relu'd ----------------
__global__ __launch_bounds__(256) void k_gemm2(const float* __restrict__ O1,
                                               const float* __restrict__ W,
                                               const float* __restrict__ dinv,
                                               unsigned short* __restrict__ H2s) {
    constexpr int R  = 32;
    constexpr int XS = HID + 4;
    __shared__ float ws[HID * OUTC];
    __shared__ float xs[R * XS];
    const int t    = threadIdx.x;
    const int row0 = blockIdx.x * R;

    for (int i = t; i < HID * OUTC / 4; i += 256)
        ((float4*)ws)[i] = ((const float4*)W)[i];
    for (int i = t; i < R * HID / 4; i += 256) {
        int r = i / (HID / 4), k4 = i % (HID / 4);
        *(float4*)&xs[r * XS + k4 * 4] =
            ((const float4*)(O1 + (size_t)(row0 + r) * HID))[k4];
    }
    __syncthreads();

    const int col0 = (t & 7) * 4;
    const int r    = t >> 3;
    float4 a = {0, 0, 0, 0};
    for (int k = 0; k < HID; ++k) {
        float4 w = *(const float4*)&ws[k * OUTC + col0];
        float x  = xs[r * XS + k];
        a.x += x * w.x; a.y += x * w.y; a.z += x * w.z; a.w += x * w.w;
    }
    const float dd = dinv[row0 + r];
    ushort4 p = {f2bf(a.x * dd), f2bf(a.y * dd), f2bf(a.z * dd), f2bf(a.w * dd)};
    *(ushort4*)(H2s + (size_t)(row0 + r) * OUTC + col0) = p;
}

// ---------------- gather2: out = dinv[d]*(H2s[d] + Σ H2s[s]) + b2 ----------------
__global__ __launch_bounds__(256) void k_gather2(const int* __restrict__ offs,
                                                 const int* __restrict__ csr,
                                                 const float* __restrict__ dinv,
                                                 const unsigned short* __restrict__ H2s,
                                                 const float* __restrict__ b,
                                                 float* __restrict__ out) {
    const int lane = threadIdx.x & 63;
    const int c    = lane & 31;
    const int half = lane >> 5;
    const int node = blockIdx.x * 4 + (threadIdx.x >> 6);
    float acc0 = (half == 0) ? bf2f(H2s[(size_t)node * OUTC + c]) : 0.0f;
    float acc1 = 0.0f;
    const int end = offs[node + 1];
    int j = offs[node] + half;
    for (; j + 6 < end; j += 8) {
        int s0 = csr[j], s1 = csr[j + 2], s2 = csr[j + 4], s3 = csr[j + 6];
        float h0 = bf2f(H2s[(size_t)s0 * OUTC + c]);
        float h1 = bf2f(H2s[(size_t)s1 * OUTC + c]);
        float h2 = bf2f(H2s[(size_t)s2 * OUTC + c]);
        float h3 = bf2f(H2s[(size_t)s3 * OUTC + c]);
        acc0 += h0 + h2;
        acc1 += h1 + h3;
    }
    for (; j < end; j += 2)
        acc0 += bf2f(H2s[(size_t)csr[j] * OUTC + c]);
    float acc = acc0 + acc1;
    acc += __shfl_down(acc, 32, 64);
    if (half == 0)
        out[(size_t)node * OUTC + c] = acc * dinv[node] + b[c];
}

extern "C" void kernel_launch(void* const* d_in, const int* in_sizes, int n_in,
                              void* d_out, int out_size, void* d_ws, size_t ws_size,
                              hipStream_t stream) {
    const float* x   = (const float*)d_in[0];
    const int*   ei  = (const int*)d_in[1];
    const float* W1  = (const float*)d_in[2];
    const float* b1  = (const float*)d_in[3];
    const float* W2  = (const float*)d_in[4];
    const float* b2  = (const float*)d_in[5];
    float*       out = (float*)d_out;

    const int* srcp = ei;
    const int* dstp = ei + E;

    char* ws = (char*)d_ws;
    int*            gcnt   = (int*)(ws + 0);                   // 784 B
    int*            bbase  = (int*)(ws + 4096);                // 788 B
    int*            cursor = (int*)(ws + 8192);                // 784 B
    int*            offs   = (int*)(ws + 16384);               // 400,004 B
    float*          dinv   = (float*)(ws + (512u << 10));      // 400 KB
    unsigned*       packed = (unsigned*)(ws + (1u << 20));     // 6.4 MB (becomes csr in place)
    unsigned short* Hs     = (unsigned short*)(ws + (8u << 20));   // 12.8 MB
    float*          O1     = (float*)(ws + (21u << 20));       // 25.6 MB -> ends 46.6 MB
    unsigned short* H2s    = Hs;                               // reuse: Hs dead after gather1
    int*            csr    = (int*)packed;

    hipMemsetAsync(gcnt, 0, NB * sizeof(int), stream);
    k_hist <<<256, 256, 0, stream>>>(dstp, gcnt);
    k_bscan<<<1, 256, 0, stream>>>(gcnt, bbase, cursor);
    k_part <<<PB, 256, 0, stream>>>(srcp, dstp, cursor, packed);
    k_build<<<NB, 512, 0, stream>>>(bbase, packed, offs, dinv);

    k_gemm1<<<N / 32, 256, 0, stream>>>(x, W1, dinv, Hs);
    k_gather1<<<N / 4, 256, 0, stream>>>(offs, csr, dinv, Hs, b1, O1);
    k_gemm2<<<N / 32, 256, 0, stream>>>(O1, W2, dinv, H2s);
    k_gather2<<<N / 4, 256, 0, stream>>>(offs, csr, dinv, H2s, b2, out);
}